// Round 22
// baseline (370.779 us; speedup 1.0000x reference)
//
#include <hip/hip_runtime.h>
#include <stdint.h>

typedef unsigned short u16;
typedef __bf16 bf16x8 __attribute__((ext_vector_type(8)));
typedef float f32x4 __attribute__((ext_vector_type(4)));

#define SEQ 2048
#define NH 8
#define NKVH 4
#define HD 256
#define WIN 1024
#define NBATCH 2

__device__ __forceinline__ u16 f2bf(float f) {
    union { float f; unsigned u; } v; v.f = f;
    unsigned r = v.u + 0x7FFFu + ((v.u >> 16) & 1u);
    return (u16)(r >> 16);
}
__device__ __forceinline__ float bf2f(u16 h) {
    union { unsigned u; float f; } v; v.u = ((unsigned)h) << 16;
    return v.f;
}
__device__ __forceinline__ bf16x8 ld8(const u16* p) {
    return *reinterpret_cast<const bf16x8*>(p);
}
__device__ __forceinline__ void split2(float f, u16& h, u16& l) {
    h = f2bf(f);
    l = f2bf(f - bf2f(h));
}
__device__ __forceinline__ void gld16(const u16* gp, u16* lp) {
    __builtin_amdgcn_global_load_lds(
        (__attribute__((address_space(1))) unsigned int*)gp,
        (__attribute__((address_space(3))) unsigned int*)lp, 16, 0, 0);
}
#define MFMA16(a, b, c) __builtin_amdgcn_mfma_f32_16x16x32_bf16((a), (b), (c), 0, 0, 0)

// ---- fused prepass: x cvt (blocks 0..8191) + 4 weight transposes ----
__global__ void k_prep(const float* __restrict__ x, u16* __restrict__ xh, u16* __restrict__ xl,
                       const float* __restrict__ wq, u16* __restrict__ wqh, u16* __restrict__ wql,
                       const float* __restrict__ wk, u16* __restrict__ wkh, u16* __restrict__ wkl,
                       const float* __restrict__ wv, u16* __restrict__ wvh,
                       const float* __restrict__ wo, u16* __restrict__ woh) {
    __shared__ float tile[64][65];
    int blk = blockIdx.x;
    const int tid = threadIdx.x;
    if (blk < 8192) {
        int i = (blk * 256 + tid) * 4;
        float4 v = *reinterpret_cast<const float4*>(x + i);
        ushort4 oh, ol;
        split2(v.x, oh.x, ol.x); split2(v.y, oh.y, ol.y);
        split2(v.z, oh.z, ol.z); split2(v.w, oh.w, ol.w);
        *reinterpret_cast<ushort4*>(xh + i) = oh;
        *reinterpret_cast<ushort4*>(xl + i) = ol;
        return;
    }
    blk -= 8192;
    const float* src; u16 *dh, *dl; int ncols, c0, k0;
    if (blk < 1024) {
        src = wq; dh = wqh; dl = wql; ncols = 2048;
        c0 = (blk & 31) * 64; k0 = (blk >> 5) * 64;
    } else if (blk < 1536) {
        blk -= 1024;
        src = wk; dh = wkh; dl = wkl; ncols = 1024;
        c0 = (blk & 15) * 64; k0 = (blk >> 4) * 64;
    } else if (blk < 2048) {
        blk -= 1536;
        src = wv; dh = wvh; dl = nullptr; ncols = 1024;
        c0 = (blk & 15) * 64; k0 = (blk >> 4) * 64;
    } else {
        blk -= 2048;
        src = wo; dh = woh; dl = nullptr; ncols = 2048;
        c0 = (blk & 31) * 64; k0 = (blk >> 5) * 64;
    }
    int tx = tid & 63, ty = tid >> 6;
    #pragma unroll
    for (int r = 0; r < 16; ++r) {
        int k = k0 + ty * 16 + r;
        tile[ty * 16 + r][tx] = src[(size_t)k * ncols + c0 + tx];
    }
    __syncthreads();
    #pragma unroll
    for (int r = 0; r < 16; ++r) {
        int c = c0 + ty * 16 + r;
        float f = tile[tx][ty * 16 + r];
        if (dl) {
            u16 h, l; split2(f, h, l);
            dh[(size_t)c * 2048 + k0 + tx] = h;
            dl[(size_t)c * 2048 + k0 + tx] = l;
        } else {
            dh[(size_t)c * 2048 + k0 + tx] = f2bf(f);
        }
    }
}

// ------- GEMM2: 128x128 single-segment (BK=64, row&7 swizzle) -------
__global__ __launch_bounds__(256, 4) void k_gemm(
        const u16* __restrict__ A0, const u16* __restrict__ B0,
        const u16* __restrict__ A1, const u16* __restrict__ B1,
        const u16* __restrict__ A2, const u16* __restrict__ B2,
        float* __restrict__ C, int M, int N, int K, int nseg, int vcol0) {
    __shared__ __align__(16) u16 sA[128 * 64];
    __shared__ __align__(16) u16 sB[128 * 64];
    const int tm = blockIdx.x * 128;
    const int tn = blockIdx.y * 128;
    const int tid = threadIdx.x;
    const int lane = tid & 63;
    const int wave = tid >> 6;
    const int wr = (wave >> 1) * 64;
    const int wc = (wave & 1) * 64;
    const int l16 = lane & 15;
    const int g = lane >> 4;
    const int srow = tid >> 3;
    const int schunk = tid & 7;
    const int nseg_eff = (tn >= vcol0) ? 1 : nseg;
    f32x4 acc[4][4] = {};

    for (int seg = 0; seg < nseg_eff; ++seg) {
        const u16* A = seg == 0 ? A0 : (seg == 1 ? A1 : A2);
        const u16* B = seg == 0 ? B0 : (seg == 1 ? B1 : B2);
        for (int k0 = 0; k0 < K; k0 += 64) {
            __syncthreads();
            #pragma unroll
            for (int i = 0; i < 4; ++i) {
                int row = i * 32 + srow;
                int cs = ((schunk ^ (row & 7)) << 3);
                gld16(A + (size_t)(tm + row) * K + k0 + cs, &sA[i * 2048 + tid * 8]);
                gld16(B + (size_t)(tn + row) * K + k0 + cs, &sB[i * 2048 + tid * 8]);
            }
            __syncthreads();
            #pragma unroll
            for (int kk = 0; kk < 2; ++kk) {
                const int j = kk * 4 + g;
                bf16x8 af[4], bfv[4];
                #pragma unroll
                for (int m = 0; m < 4; ++m) {
                    int r = wr + m * 16 + l16;
                    af[m] = ld8(&sA[r * 64 + ((j ^ (r & 7)) << 3)]);
                }
                #pragma unroll
                for (int n = 0; n < 4; ++n) {
                    int r = wc + n * 16 + l16;
                    bfv[n] = ld8(&sB[r * 64 + ((j ^ (r & 7)) << 3)]);
                }
                #pragma unroll
                for (int m = 0; m < 4; ++m)
                    #pragma unroll
                    for (int n = 0; n < 4; ++n)
                        acc[m][n] = MFMA16(af[m], bfv[n], acc[m][n]);
            }
        }
    }
    int rbase = tm + wr + g * 4;
    int cbase = tn + wc + l16;
    #pragma unroll
    for (int m = 0; m < 4; ++m)
        #pragma unroll
        for (int n = 0; n < 4; ++n)
            #pragma unroll
            for (int r = 0; r < 4; ++r)
                C[(size_t)(rbase + m * 16 + r) * N + cbase + n * 16] = acc[m][n][r];
}

// ------- GEMM1: 128x128, BK=32, 4 LDS buffers (Ah, Al, Bh, Bl), single pass.
// ------- q/k columns: 48 MFMA per step from 16 ds_reads (0.333 reads/MFMA);
// ------- 32KB LDS -> 3 blocks/CU. v columns: Ah*Bh only.
// ------- 64B rows: swizzle slot = chunk ^ ((row>>1)&3)  (2-way bank alias, free).
__global__ __launch_bounds__(256, 3) void k_gemm1(
        const u16* __restrict__ Ah, const u16* __restrict__ Al,
        const u16* __restrict__ Bh, const u16* __restrict__ Bl,
        float* __restrict__ C, int M, int N, int K, int vcol0) {
    __shared__ __align__(16) u16 sAh[128 * 32];
    __shared__ __align__(16) u16 sAl[128 * 32];
    __shared__ __align__(16) u16 sBh[128 * 32];
    __shared__ __align__(16) u16 sBl[128 * 32];
    const int tm = blockIdx.x * 128;
    const int tn = blockIdx.y * 128;
    const int tid = threadIdx.x;
    const int lane = tid & 63;
    const int wave = tid >> 6;
    const int wr = (wave >> 1) * 64;
    const int wc = (wave & 1) * 64;
    const int l16 = lane & 15;
    const int g = lane >> 4;
    const bool qk = (tn < vcol0);        // block-uniform
    f32x4 acc[4][4] = {};

    for (int k0 = 0; k0 < K; k0 += 32) {
        __syncthreads();
        #pragma unroll
        for (int i = 0; i < 2; ++i) {
            int u = i * 256 + tid;          // 16B unit index within tile
            int row = u >> 2, chunk = u & 3;
            int cs = ((chunk ^ ((row >> 1) & 3)) << 3);
            gld16(Ah + (size_t)(tm + row) * K + k0 + cs, &sAh[u * 8]);
            gld16(Bh + (size_t)(tn + row) * K + k0 + cs, &sBh[u * 8]);
            if (qk) {
                gld16(Al + (size_t)(tm + row) * K + k0 + cs, &sAl[u * 8]);
                gld16(Bl + (size_t)(tn + row) * K + k0 + cs, &sBl[u * 8]);
            }
        }
        __syncthreads();
        bf16x8 afh[4], bfh[4];
        #pragma unroll
        for (int m = 0; m < 4; ++m) {
            int r = wr + m * 16 + l16;
            afh[m] = ld8(&sAh[r * 32 + ((g ^ ((r >> 1) & 3)) << 3)]);
        }
        #pragma unroll
        for (int n = 0; n < 4; ++n) {
            int r = wc + n * 16 + l16;
            bfh[n] = ld8(&sBh[r * 32 + ((g ^ ((r >> 1) & 3)) << 3)]);
        }
        // product 1: Ah * Bh
        #pragma unroll
        for (int m = 0; m < 4; ++m)
            #pragma unroll
            for (int n = 0; n < 4; ++n)
                acc[m][n] = MFMA16(afh[m], bfh[n], acc[m][n]);
        if (qk) {
            // product 2: Al * Bh (reuse bfh)
            bf16x8 afl[4];
            #pragma unroll
            for (int m = 0; m < 4; ++m) {
                int r = wr + m * 16 + l16;
                afl[m] = ld8(&sAl[r * 32 + ((g ^ ((r >> 1) & 3)) << 3)]);
            }
            #pragma unroll
            for (int m = 0; m < 4; ++m)
                #pragma unroll
                for (int n = 0; n < 4; ++n)
                    acc[m][n] = MFMA16(afl[m], bfh[n], acc[m][n]);
            // product 3: Ah * Bl (reuse afh)
            bf16x8 bfl[4];
            #pragma unroll
            for (int n = 0; n < 4; ++n) {
                int r = wc + n * 16 + l16;
                bfl[n] = ld8(&sBl[r * 32 + ((g ^ ((r >> 1) & 3)) << 3)]);
            }
            #pragma unroll
            for (int m = 0; m < 4; ++m)
                #pragma unroll
                for (int n = 0; n < 4; ++n)
                    acc[m][n] = MFMA16(afh[m], bfl[n], acc[m][n]);
        }
    }

    int rbase = tm + wr + g * 4;
    int cbase = tn + wc + l16;
    #pragma unroll
    for (int m = 0; m < 4; ++m)
        #pragma unroll
        for (int n = 0; n < 4; ++n)
            #pragma unroll
            for (int r = 0; r < 4; ++r)
                C[(size_t)(rbase + m * 16 + r) * N + cbase + n * 16] = acc[m][n][r];
}

// ---- fused RMSNorm+RoPE (blocks 0..12287) + V transpose (blocks 12288..13311) ----
// Q layout: [b][h][seq][256] plain.  K layout: [b][hk][seq][256] with 16B-chunk
// XOR swizzle baked in: element d stored at ((d>>3)^(t&7))<<3 | (d&7).
__global__ void k_nrvt(const float* __restrict__ qkv, const int* __restrict__ pos,
                       const float* __restrict__ qscale, const float* __restrict__ kscale,
                       u16* __restrict__ Qh, u16* __restrict__ Ql,
                       u16* __restrict__ Kh, u16* __restrict__ Kl,
                       u16* __restrict__ VT) {
    __shared__ float tile[64][65];
    const int blk = blockIdx.x;
    const int tid = threadIdx.x;
    if (blk >= 12288) {
        int idx = blk - 12288;
        int t0 = (idx & 31) * 64;
        int d0 = ((idx >> 5) & 3) * 64;
        int bh = idx >> 7;
        int b = bh >> 2, h = bh & 3;
        int tx = tid & 63, ty = tid >> 6;
        #pragma unroll
        for (int r = 0; r < 16; ++r) {
            int t = t0 + ty * 16 + r;
            tile[ty * 16 + r][tx] = qkv[(size_t)(b * SEQ + t) * 4096 + 3072 + h * 256 + d0 + tx];
        }
        __syncthreads();
        #pragma unroll
        for (int r = 0; r < 16; ++r) {
            int d = d0 + ty * 16 + r;
            VT[((size_t)bh * 256 + d) * SEQ + t0 + tx] = f2bf(tile[tx][ty * 16 + r]);
        }
        return;
    }
    int wid = blk * 4 + (tid >> 6);
    int lane = tid & 63;
    const int nq = NBATCH * SEQ * NH;
    const int ntot = NBATCH * SEQ * (NH + NKVH);
    if (wid >= ntot) return;
    const float* scale;
    const float* src;
    u16 *dh, *dl;
    int bt, isq;
    if (wid < nq) {
        int h = wid % NH; bt = wid / NH; isq = 1;
        scale = qscale;
        src = qkv + (size_t)bt * 4096 + h * 256;
        int b = bt >> 11, t = bt & 2047;
        size_t off = (((size_t)b * NH + h) * SEQ + t) * 256;
        dh = Qh + off; dl = Ql + off;
    } else {
        int w2 = wid - nq;
        int h = w2 % NKVH; bt = w2 / NKVH; isq = 0;
        scale = kscale;
        src = qkv + (size_t)bt * 4096 + 2048 + h * 256;
        int b = bt >> 11, t = bt & 2047;
        size_t off = (((size_t)b * NKVH + h) * SEQ + t) * 256;
        dh = Kh + off; dl = Kl + off;
    }
    const int t7 = bt & 7;
    float e[4];
    float ssq = 0.f;
    #pragma unroll
    for (int j = 0; j < 4; ++j) { e[j] = src[lane + 64 * j]; ssq += e[j] * e[j]; }
    #pragma unroll
    for (int off = 1; off < 64; off <<= 1) ssq += __shfl_xor(ssq, off);
    float inv = rsqrtf(ssq * (1.0f / 256.0f) + 1e-6f);
    #pragma unroll
    for (int j = 0; j < 4; ++j) e[j] = e[j] * inv * scale[lane + 64 * j];
    float p = (float)pos[bt];
    float fr0 = powf(10000.0f, (2.0f * lane) * (1.0f / 256.0f));
    float fr1 = powf(10000.0f, (2.0f * (lane + 64)) * (1.0f / 256.0f));
    float s0, c0, s1, c1;
    sincosf(p / fr0, &s0, &c0);
    sincosf(p / fr1, &s1, &c1);
    float rv[4];
    rv[0] = e[0] * c0 - e[2] * s0;
    rv[1] = e[1] * c1 - e[3] * s1;
    rv[2] = e[2] * c0 + e[0] * s0;
    rv[3] = e[3] * c1 + e[1] * s1;
    #pragma unroll
    for (int j = 0; j < 4; ++j) {
        int d = lane + 64 * j;
        int dd = isq ? d : ((((d >> 3) ^ t7) << 3) | (d & 7));
        u16 h, l; split2(rv[j], h, l);
        dh[dd] = h; dl[dd] = l;
    }
}

// ---- fused attention (best, R14): 4 waves, 64 q/block, KVBLK=32. ALL MFMA
// ---- operands from LDS (K_hi, K_lo, V staged via global_load_lds). ----
__global__ __launch_bounds__(256, 2) void k_attn(const u16* __restrict__ Qh, const u16* __restrict__ Ql,
                                                 const u16* __restrict__ Kh, const u16* __restrict__ Kl,
                                                 const u16* __restrict__ VT,
                                                 u16* __restrict__ Out) {
    __shared__ __align__(16) u16 sKh[32 * 256];
    __shared__ __align__(16) u16 sKl[32 * 256];
    __shared__ __align__(16) u16 sV[256 * 32];   // [d][key] 64B rows (bank-balanced)
    __shared__ __align__(16) u16 pls[4][16][40];

    const int id = blockIdx.x;
    const int xcd = id & 7;
    const int j = id >> 3;               // 0..63
    const int b  = xcd >> 2;
    const int hk = xcd & 3;
    const int hq = hk * 2 + (j & 1);
    const int qt = 31 - (j >> 1);        // 31..0  (heavy first)
    const int tid = threadIdx.x;
    const int lane = tid & 63;
    const int wave = tid >> 6;           // 0..3
    const int q0b = qt * 64;
    const int q0 = q0b + wave * 16;
    const int l16 = lane & 15;
    const int g = lane >> 4;

    bf16x8 qfh[8], qfl[8];
    {
        size_t qoff = (((size_t)b * NH + hq) * SEQ + q0 + l16) * 256 + g * 8;
        #pragma unroll
        for (int kk = 0; kk < 8; ++kk) {
            qfh[kk] = ld8(Qh + qoff + kk * 32);
            qfl[kk] = ld8(Ql + qoff + kk * 32);
        }
    }

    float ssum[4] = {0.f, 0.f, 0.f, 0.f};
    f32x4 o[16] = {};

    const u16* kgh = Kh + (((size_t)b * NKVH + hk) * SEQ) * 256;
    const u16* kgl = Kl + (((size_t)b * NKVH + hk) * SEQ) * 256;
    const u16* vg  = VT + ((size_t)(b * NKVH + hk) * 256) * SEQ;

    int s_lo = q0b - (WIN - 1); if (s_lo < 0) s_lo = 0; s_lo &= ~31;
    const int s_hi = q0b + 63;
    const int ntiles = (s_hi - s_lo) / 32 + 1;

    for (int t = 0; t < ntiles; ++t) {
        const int s0 = s_lo + t * 32;
        __syncthreads();
        {
            const u16* srch = kgh + (size_t)s0 * 256 + tid * 8;
            const u16* srcl = kgl + (size_t)s0 * 256 + tid * 8;
            #pragma unroll
            for (int i = 0; i < 4; ++i) {
                gld16(srch + i * 2048, &sKh[i * 2048 + tid * 8]);
                gld16(srcl + i * 2048, &sKl[i * 2048 + tid * 8]);
            }
            const u16* srcv = vg + (size_t)(tid >> 2) * SEQ + s0 + (tid & 3) * 8;
            #pragma unroll
            for (int i = 0; i < 4; ++i)
                gld16(srcv + (size_t)i * 64 * SEQ, &sV[i * 2048 + tid * 8]);
        }
        __syncthreads();

        if (s0 <= q0 + 15 && s0 + 31 >= q0 - (WIN - 1)) {
            f32x4 c[2] = {};
            __builtin_amdgcn_s_setprio(1);
            #pragma unroll
            for (int kk = 0; kk < 8; ++kk) {
                #pragma unroll
                for (int cc = 0; cc < 2; ++cc) {
                    int row = cc * 16 + l16;
                    int slot = ((kk * 4 + g) ^ (row & 7)) << 3;
                    bf16x8 kh = ld8(&sKh[row * 256 + slot]);
                    bf16x8 kl = ld8(&sKl[row * 256 + slot]);
                    c[cc] = MFMA16(qfh[kk], kh, c[cc]);
                    c[cc] = MFMA16(qfl[kk], kh, c[cc]);
                    c[cc] = MFMA16(qfh[kk], kl, c[cc]);
                }
            }
            __builtin_amdgcn_s_setprio(0);

            const bool full = (s0 + 31 <= q0) && (s0 >= q0 + 15 - (WIN - 1));
            #pragma unroll
            for (int r = 0; r < 4; ++r) {
                int qp = q0 + g * 4 + r;
                int row = g * 4 + r;
                #pragma unroll
                for (int cc = 0; cc < 2; ++cc) {
                    float ev = __expf(c[cc][r] * 0.04f);                       // e^{l/25}
                    float v = 50.f - 100.f * __builtin_amdgcn_rcpf(ev + 1.f);  // 50*tanh(l/50)
                    if (!full) {
                        int sp = s0 + cc * 16 + l16;
                        bool valid = (sp <= qp) && (sp > qp - WIN);
                        v = valid ? v : -1e30f;
                    }
                    float p = __expf(v - 20.f);       // fixed shift; masked -> exactly 0
                    u16 pb = f2bf(p);
                    pls[wave][row][cc * 16 + l16] = pb;
                    ssum[r] += bf2f(pb);
                }
            }
            bf16x8 pa = ld8(&pls[wave][l16][g * 8]);
            __builtin_amdgcn_s_setprio(1);
            #pragma unroll
            for (int jb = 0; jb < 16; ++jb)
                o[jb] = MFMA16(pa, ld8(&sV[(jb * 16 + l16) * 32 + g * 8]), o[jb]);
            __builtin_amdgcn_s_setprio(0);
        }
    }

    #pragma unroll
    for (int off = 1; off < 16; off <<= 1)
        #pragma unroll
        for (int r = 0; r < 4; ++r) ssum[r] += __shfl_xor(ssum[r], off);
    #pragma unroll
    for (int r = 0; r < 4; ++r) {
        float inv = 1.0f / ssum[r];
        int trow = q0 + g * 4 + r;
        size_t base = ((size_t)(b * SEQ + trow) * NH + hq) * 256 + l16;
        #pragma unroll
        for (int jb = 0; jb < 16; ++jb)
            Out[base + jb * 16] = f2bf(o[jb][r] * inv);
    }
}

extern "C" void kernel_launch(void* const* d_in, const int* in_sizes, int n_in,
                              void* d_out, int out_size, void* d_ws, size_t ws_size,
                              hipStream_t stream) {
    (void)in_sizes; (void)n_in; (void)out_size; (void)ws_size;
    const float* x  = (const float*)d_in[0];
    const int* pos  = (const int*)d_in[1];
    const float* wq = (const float*)d_in[3];
    const float* wk = (const float*)d_in[4];
    const float* wv = (const float*)d_in[5];
    const float* wo = (const float*)d_in[6];
    const float* qs = (const float*)d_in[7];
    const float* ks = (const float*)d_in[8];

    const size_t MX = (size_t)4096 * 2048;   // 8,388,608
    const size_t MW = (size_t)2048 * 2048;   // 4,194,304

    u16* xh  = (u16*)d_ws;
    u16* xl  = xh + MX;
    u16* wth = xl + MX;
    u16* wtl = wth + MX;
    u16* woth = wtl + MX;
    u16* wotl = woth + MW;
    float* qkv = (float*)(wotl + MW);

    u16* qbh = xh;               // 8M
    u16* qbl = qbh + MX;         // 8M
    u16* kbh = qbl + MX;         // 4M
    u16* kbl = kbh + MX / 2;     // 4M
    u16* vt  = kbl + MX / 2;     // 4M
    u16* ao  = (u16*)qkv;        // aliases region C (plain bf16)

    k_prep<<<11264, 256, 0, stream>>>(x, xh, xl,
                                      wq, wth, wtl,
                                      wk, wth + MW, wtl + MW,
                                      wv, wth + MW + MW / 2,
                                      wo, woth);
    k_gemm1<<<dim3(32, 32), 256, 0, stream>>>(xh, xl, wth, wtl, qkv,
                                              4096, 4096, 2048, 3072);
    k_nrvt<<<13312, 256, 0, stream>>>(qkv, pos, qs, ks, qbh, qbl, kbh, kbl, vt);
    k_attn<<<512, 256, 0, stream>>>(qbh, qbl, kbh, kbl, vt, ao);
    k_gemm<<<dim3(32, 16), 256, 0, stream>>>(ao, woth, ao, woth, ao, wotl, (float*)d_out,
                                             4096, 2048, 2048, 1, 2048);
}

// Round 23
// 360.701 us; speedup vs baseline: 1.0279x; 1.0279x over previous
//
#include <hip/hip_runtime.h>
#include <stdint.h>

typedef unsigned short u16;
typedef __bf16 bf16x8 __attribute__((ext_vector_type(8)));
typedef float f32x4 __attribute__((ext_vector_type(4)));

#define SEQ 2048
#define NH 8
#define NKVH 4
#define HD 256
#define WIN 1024
#define NBATCH 2

__device__ __forceinline__ u16 f2bf(float f) {
    union { float f; unsigned u; } v; v.f = f;
    unsigned r = v.u + 0x7FFFu + ((v.u >> 16) & 1u);
    return (u16)(r >> 16);
}
__device__ __forceinline__ float bf2f(u16 h) {
    union { unsigned u; float f; } v; v.u = ((unsigned)h) << 16;
    return v.f;
}
__device__ __forceinline__ bf16x8 ld8(const u16* p) {
    return *reinterpret_cast<const bf16x8*>(p);
}
__device__ __forceinline__ void split2(float f, u16& h, u16& l) {
    h = f2bf(f);
    l = f2bf(f - bf2f(h));
}
__device__ __forceinline__ void gld16(const u16* gp, u16* lp) {
    __builtin_amdgcn_global_load_lds(
        (__attribute__((address_space(1))) unsigned int*)gp,
        (__attribute__((address_space(3))) unsigned int*)lp, 16, 0, 0);
}
#define MFMA16(a, b, c) __builtin_amdgcn_mfma_f32_16x16x32_bf16((a), (b), (c), 0, 0, 0)

// ---- fused prepass: x cvt (blocks 0..8191) + 4 weight transposes ----
__global__ void k_prep(const float* __restrict__ x, u16* __restrict__ xh, u16* __restrict__ xl,
                       const float* __restrict__ wq, u16* __restrict__ wqh, u16* __restrict__ wql,
                       const float* __restrict__ wk, u16* __restrict__ wkh, u16* __restrict__ wkl,
                       const float* __restrict__ wv, u16* __restrict__ wvh,
                       const float* __restrict__ wo, u16* __restrict__ woh) {
    __shared__ float tile[64][65];
    int blk = blockIdx.x;
    const int tid = threadIdx.x;
    if (blk < 8192) {
        int i = (blk * 256 + tid) * 4;
        float4 v = *reinterpret_cast<const float4*>(x + i);
        ushort4 oh, ol;
        split2(v.x, oh.x, ol.x); split2(v.y, oh.y, ol.y);
        split2(v.z, oh.z, ol.z); split2(v.w, oh.w, ol.w);
        *reinterpret_cast<ushort4*>(xh + i) = oh;
        *reinterpret_cast<ushort4*>(xl + i) = ol;
        return;
    }
    blk -= 8192;
    const float* src; u16 *dh, *dl; int ncols, c0, k0;
    if (blk < 1024) {
        src = wq; dh = wqh; dl = wql; ncols = 2048;
        c0 = (blk & 31) * 64; k0 = (blk >> 5) * 64;
    } else if (blk < 1536) {
        blk -= 1024;
        src = wk; dh = wkh; dl = wkl; ncols = 1024;
        c0 = (blk & 15) * 64; k0 = (blk >> 4) * 64;
    } else if (blk < 2048) {
        blk -= 1536;
        src = wv; dh = wvh; dl = nullptr; ncols = 1024;
        c0 = (blk & 15) * 64; k0 = (blk >> 4) * 64;
    } else {
        blk -= 2048;
        src = wo; dh = woh; dl = nullptr; ncols = 2048;
        c0 = (blk & 31) * 64; k0 = (blk >> 5) * 64;
    }
    int tx = tid & 63, ty = tid >> 6;
    #pragma unroll
    for (int r = 0; r < 16; ++r) {
        int k = k0 + ty * 16 + r;
        tile[ty * 16 + r][tx] = src[(size_t)k * ncols + c0 + tx];
    }
    __syncthreads();
    #pragma unroll
    for (int r = 0; r < 16; ++r) {
        int c = c0 + ty * 16 + r;
        float f = tile[tx][ty * 16 + r];
        if (dl) {
            u16 h, l; split2(f, h, l);
            dh[(size_t)c * 2048 + k0 + tx] = h;
            dl[(size_t)c * 2048 + k0 + tx] = l;
        } else {
            dh[(size_t)c * 2048 + k0 + tx] = f2bf(f);
        }
    }
}

// ------- GEMM2: 128x128 single-segment (BK=64, row&7 swizzle) -------
__global__ __launch_bounds__(256, 4) void k_gemm(
        const u16* __restrict__ A0, const u16* __restrict__ B0,
        const u16* __restrict__ A1, const u16* __restrict__ B1,
        const u16* __restrict__ A2, const u16* __restrict__ B2,
        float* __restrict__ C, int M, int N, int K, int nseg, int vcol0) {
    __shared__ __align__(16) u16 sA[128 * 64];
    __shared__ __align__(16) u16 sB[128 * 64];
    const int tm = blockIdx.x * 128;
    const int tn = blockIdx.y * 128;
    const int tid = threadIdx.x;
    const int lane = tid & 63;
    const int wave = tid >> 6;
    const int wr = (wave >> 1) * 64;
    const int wc = (wave & 1) * 64;
    const int l16 = lane & 15;
    const int g = lane >> 4;
    const int srow = tid >> 3;
    const int schunk = tid & 7;
    const int nseg_eff = (tn >= vcol0) ? 1 : nseg;
    f32x4 acc[4][4] = {};

    for (int seg = 0; seg < nseg_eff; ++seg) {
        const u16* A = seg == 0 ? A0 : (seg == 1 ? A1 : A2);
        const u16* B = seg == 0 ? B0 : (seg == 1 ? B1 : B2);
        for (int k0 = 0; k0 < K; k0 += 64) {
            __syncthreads();
            #pragma unroll
            for (int i = 0; i < 4; ++i) {
                int row = i * 32 + srow;
                int cs = ((schunk ^ (row & 7)) << 3);
                gld16(A + (size_t)(tm + row) * K + k0 + cs, &sA[i * 2048 + tid * 8]);
                gld16(B + (size_t)(tn + row) * K + k0 + cs, &sB[i * 2048 + tid * 8]);
            }
            __syncthreads();
            #pragma unroll
            for (int kk = 0; kk < 2; ++kk) {
                const int j = kk * 4 + g;
                bf16x8 af[4], bfv[4];
                #pragma unroll
                for (int m = 0; m < 4; ++m) {
                    int r = wr + m * 16 + l16;
                    af[m] = ld8(&sA[r * 64 + ((j ^ (r & 7)) << 3)]);
                }
                #pragma unroll
                for (int n = 0; n < 4; ++n) {
                    int r = wc + n * 16 + l16;
                    bfv[n] = ld8(&sB[r * 64 + ((j ^ (r & 7)) << 3)]);
                }
                #pragma unroll
                for (int m = 0; m < 4; ++m)
                    #pragma unroll
                    for (int n = 0; n < 4; ++n)
                        acc[m][n] = MFMA16(af[m], bfv[n], acc[m][n]);
            }
        }
    }
    int rbase = tm + wr + g * 4;
    int cbase = tn + wc + l16;
    #pragma unroll
    for (int m = 0; m < 4; ++m)
        #pragma unroll
        for (int n = 0; n < 4; ++n)
            #pragma unroll
            for (int r = 0; r < 4; ++r)
                C[(size_t)(rbase + m * 16 + r) * N + cbase + n * 16] = acc[m][n][r];
}

// ------- GEMM1 (best, R17): 128x128, 3-buffer merged pass1 + Bl pass2 -------
__global__ __launch_bounds__(256, 3) void k_gemm1(
        const u16* __restrict__ Ah, const u16* __restrict__ Al,
        const u16* __restrict__ Bh, const u16* __restrict__ Bl,
        float* __restrict__ C, int M, int N, int K, int vcol0) {
    __shared__ __align__(16) u16 sAh[128 * 64];
    __shared__ __align__(16) u16 sAl[128 * 64];
    __shared__ __align__(16) u16 sB[128 * 64];
    const int tm = blockIdx.x * 128;
    const int tn = blockIdx.y * 128;
    const int tid = threadIdx.x;
    const int lane = tid & 63;
    const int wave = tid >> 6;
    const int wr = (wave >> 1) * 64;
    const int wc = (wave & 1) * 64;
    const int l16 = lane & 15;
    const int g = lane >> 4;
    const int srow = tid >> 3;
    const int schunk = tid & 7;
    const bool qk = (tn < vcol0);        // block-uniform
    f32x4 acc[4][4] = {};

    // ---- pass 1: (Ah [+ Al]) * Bh ----
    for (int k0 = 0; k0 < K; k0 += 64) {
        __syncthreads();
        #pragma unroll
        for (int i = 0; i < 4; ++i) {
            int row = i * 32 + srow;
            int cs = ((schunk ^ (row & 7)) << 3);
            gld16(Ah + (size_t)(tm + row) * K + k0 + cs, &sAh[i * 2048 + tid * 8]);
            if (qk)
                gld16(Al + (size_t)(tm + row) * K + k0 + cs, &sAl[i * 2048 + tid * 8]);
            gld16(Bh + (size_t)(tn + row) * K + k0 + cs, &sB[i * 2048 + tid * 8]);
        }
        __syncthreads();
        #pragma unroll
        for (int kk = 0; kk < 2; ++kk) {
            const int j = kk * 4 + g;
            bf16x8 bfv[4], af[4];
            #pragma unroll
            for (int n = 0; n < 4; ++n) {
                int r = wc + n * 16 + l16;
                bfv[n] = ld8(&sB[r * 64 + ((j ^ (r & 7)) << 3)]);
            }
            #pragma unroll
            for (int m = 0; m < 4; ++m) {
                int r = wr + m * 16 + l16;
                af[m] = ld8(&sAh[r * 64 + ((j ^ (r & 7)) << 3)]);
            }
            #pragma unroll
            for (int m = 0; m < 4; ++m)
                #pragma unroll
                for (int n = 0; n < 4; ++n)
                    acc[m][n] = MFMA16(af[m], bfv[n], acc[m][n]);
            if (qk) {
                bf16x8 afl[4];
                #pragma unroll
                for (int m = 0; m < 4; ++m) {
                    int r = wr + m * 16 + l16;
                    afl[m] = ld8(&sAl[r * 64 + ((j ^ (r & 7)) << 3)]);
                }
                #pragma unroll
                for (int m = 0; m < 4; ++m)
                    #pragma unroll
                    for (int n = 0; n < 4; ++n)
                        acc[m][n] = MFMA16(afl[m], bfv[n], acc[m][n]);
            }
        }
    }

    // ---- pass 2 (q/k only): Ah * Bl ----
    if (qk) {
        for (int k0 = 0; k0 < K; k0 += 64) {
            __syncthreads();
            #pragma unroll
            for (int i = 0; i < 4; ++i) {
                int row = i * 32 + srow;
                int cs = ((schunk ^ (row & 7)) << 3);
                gld16(Ah + (size_t)(tm + row) * K + k0 + cs, &sAh[i * 2048 + tid * 8]);
                gld16(Bl + (size_t)(tn + row) * K + k0 + cs, &sB[i * 2048 + tid * 8]);
            }
            __syncthreads();
            #pragma unroll
            for (int kk = 0; kk < 2; ++kk) {
                const int j = kk * 4 + g;
                bf16x8 bfv[4], af[4];
                #pragma unroll
                for (int n = 0; n < 4; ++n) {
                    int r = wc + n * 16 + l16;
                    bfv[n] = ld8(&sB[r * 64 + ((j ^ (r & 7)) << 3)]);
                }
                #pragma unroll
                for (int m = 0; m < 4; ++m) {
                    int r = wr + m * 16 + l16;
                    af[m] = ld8(&sAh[r * 64 + ((j ^ (r & 7)) << 3)]);
                }
                #pragma unroll
                for (int m = 0; m < 4; ++m)
                    #pragma unroll
                    for (int n = 0; n < 4; ++n)
                        acc[m][n] = MFMA16(af[m], bfv[n], acc[m][n]);
            }
        }
    }

    int rbase = tm + wr + g * 4;
    int cbase = tn + wc + l16;
    #pragma unroll
    for (int m = 0; m < 4; ++m)
        #pragma unroll
        for (int n = 0; n < 4; ++n)
            #pragma unroll
            for (int r = 0; r < 4; ++r)
                C[(size_t)(rbase + m * 16 + r) * N + cbase + n * 16] = acc[m][n][r];
}

// ---- fused RMSNorm+RoPE (blocks 0..12287) + V transpose (blocks 12288..13311) ----
// Q layout: [b][h][seq][256] plain.  K layout: [b][hk][seq][256] with 16B-chunk
// XOR swizzle baked in: element d stored at ((d>>3)^(t&7))<<3 | (d&7).
__global__ void k_nrvt(const float* __restrict__ qkv, const int* __restrict__ pos,
                       const float* __restrict__ qscale, const float* __restrict__ kscale,
                       u16* __restrict__ Qh, u16* __restrict__ Ql,
                       u16* __restrict__ Kh, u16* __restrict__ Kl,
                       u16* __restrict__ VT) {
    __shared__ float tile[64][65];
    const int blk = blockIdx.x;
    const int tid = threadIdx.x;
    if (blk >= 12288) {
        int idx = blk - 12288;
        int t0 = (idx & 31) * 64;
        int d0 = ((idx >> 5) & 3) * 64;
        int bh = idx >> 7;
        int b = bh >> 2, h = bh & 3;
        int tx = tid & 63, ty = tid >> 6;
        #pragma unroll
        for (int r = 0; r < 16; ++r) {
            int t = t0 + ty * 16 + r;
            tile[ty * 16 + r][tx] = qkv[(size_t)(b * SEQ + t) * 4096 + 3072 + h * 256 + d0 + tx];
        }
        __syncthreads();
        #pragma unroll
        for (int r = 0; r < 16; ++r) {
            int d = d0 + ty * 16 + r;
            VT[((size_t)bh * 256 + d) * SEQ + t0 + tx] = f2bf(tile[tx][ty * 16 + r]);
        }
        return;
    }
    int wid = blk * 4 + (tid >> 6);
    int lane = tid & 63;
    const int nq = NBATCH * SEQ * NH;
    const int ntot = NBATCH * SEQ * (NH + NKVH);
    if (wid >= ntot) return;
    const float* scale;
    const float* src;
    u16 *dh, *dl;
    int bt, isq;
    if (wid < nq) {
        int h = wid % NH; bt = wid / NH; isq = 1;
        scale = qscale;
        src = qkv + (size_t)bt * 4096 + h * 256;
        int b = bt >> 11, t = bt & 2047;
        size_t off = (((size_t)b * NH + h) * SEQ + t) * 256;
        dh = Qh + off; dl = Ql + off;
    } else {
        int w2 = wid - nq;
        int h = w2 % NKVH; bt = w2 / NKVH; isq = 0;
        scale = kscale;
        src = qkv + (size_t)bt * 4096 + 2048 + h * 256;
        int b = bt >> 11, t = bt & 2047;
        size_t off = (((size_t)b * NKVH + h) * SEQ + t) * 256;
        dh = Kh + off; dl = Kl + off;
    }
    const int t7 = bt & 7;
    float e[4];
    float ssq = 0.f;
    #pragma unroll
    for (int j = 0; j < 4; ++j) { e[j] = src[lane + 64 * j]; ssq += e[j] * e[j]; }
    #pragma unroll
    for (int off = 1; off < 64; off <<= 1) ssq += __shfl_xor(ssq, off);
    float inv = rsqrtf(ssq * (1.0f / 256.0f) + 1e-6f);
    #pragma unroll
    for (int j = 0; j < 4; ++j) e[j] = e[j] * inv * scale[lane + 64 * j];
    float p = (float)pos[bt];
    float fr0 = powf(10000.0f, (2.0f * lane) * (1.0f / 256.0f));
    float fr1 = powf(10000.0f, (2.0f * (lane + 64)) * (1.0f / 256.0f));
    float s0, c0, s1, c1;
    sincosf(p / fr0, &s0, &c0);
    sincosf(p / fr1, &s1, &c1);
    float rv[4];
    rv[0] = e[0] * c0 - e[2] * s0;
    rv[1] = e[1] * c1 - e[3] * s1;
    rv[2] = e[2] * c0 + e[0] * s0;
    rv[3] = e[3] * c1 + e[1] * s1;
    #pragma unroll
    for (int j = 0; j < 4; ++j) {
        int d = lane + 64 * j;
        int dd = isq ? d : ((((d >> 3) ^ t7) << 3) | (d & 7));
        u16 h, l; split2(rv[j], h, l);
        dh[dd] = h; dl[dd] = l;
    }
}

// ---- fused attention (best, R14): 4 waves, 64 q/block, KVBLK=32. ALL MFMA
// ---- operands from LDS (K_hi, K_lo, V staged via global_load_lds). ----
__global__ __launch_bounds__(256, 2) void k_attn(const u16* __restrict__ Qh, const u16* __restrict__ Ql,
                                                 const u16* __restrict__ Kh, const u16* __restrict__ Kl,
                                                 const u16* __restrict__ VT,
                                                 u16* __restrict__ Out) {
    __shared__ __align__(16) u16 sKh[32 * 256];
    __shared__ __align__(16) u16 sKl[32 * 256];
    __shared__ __align__(16) u16 sV[256 * 32];   // [d][key] 64B rows (bank-balanced)
    __shared__ __align__(16) u16 pls[4][16][40];

    const int id = blockIdx.x;
    const int xcd = id & 7;
    const int j = id >> 3;               // 0..63
    const int b  = xcd >> 2;
    const int hk = xcd & 3;
    const int hq = hk * 2 + (j & 1);
    const int qt = 31 - (j >> 1);        // 31..0  (heavy first)
    const int tid = threadIdx.x;
    const int lane = tid & 63;
    const int wave = tid >> 6;           // 0..3
    const int q0b = qt * 64;
    const int q0 = q0b + wave * 16;
    const int l16 = lane & 15;
    const int g = lane >> 4;

    bf16x8 qfh[8], qfl[8];
    {
        size_t qoff = (((size_t)b * NH + hq) * SEQ + q0 + l16) * 256 + g * 8;
        #pragma unroll
        for (int kk = 0; kk < 8; ++kk) {
            qfh[kk] = ld8(Qh + qoff + kk * 32);
            qfl[kk] = ld8(Ql + qoff + kk * 32);
        }
    }

    float ssum[4] = {0.f, 0.f, 0.f, 0.f};
    f32x4 o[16] = {};

    const u16* kgh = Kh + (((size_t)b * NKVH + hk) * SEQ) * 256;
    const u16* kgl = Kl + (((size_t)b * NKVH + hk) * SEQ) * 256;
    const u16* vg  = VT + ((size_t)(b * NKVH + hk) * 256) * SEQ;

    int s_lo = q0b - (WIN - 1); if (s_lo < 0) s_lo = 0; s_lo &= ~31;
    const int s_hi = q0b + 63;
    const int ntiles = (s_hi - s_lo) / 32 + 1;

    for (int t = 0; t < ntiles; ++t) {
        const int s0 = s_lo + t * 32;
        __syncthreads();
        {
            const u16* srch = kgh + (size_t)s0 * 256 + tid * 8;
            const u16* srcl = kgl + (size_t)s0 * 256 + tid * 8;
            #pragma unroll
            for (int i = 0; i < 4; ++i) {
                gld16(srch + i * 2048, &sKh[i * 2048 + tid * 8]);
                gld16(srcl + i * 2048, &sKl[i * 2048 + tid * 8]);
            }
            const u16* srcv = vg + (size_t)(tid >> 2) * SEQ + s0 + (tid & 3) * 8;
            #pragma unroll
            for (int i = 0; i < 4; ++i)
                gld16(srcv + (size_t)i * 64 * SEQ, &sV[i * 2048 + tid * 8]);
        }
        __syncthreads();

        if (s0 <= q0 + 15 && s0 + 31 >= q0 - (WIN - 1)) {
            f32x4 c[2] = {};
            __builtin_amdgcn_s_setprio(1);
            #pragma unroll
            for (int kk = 0; kk < 8; ++kk) {
                #pragma unroll
                for (int cc = 0; cc < 2; ++cc) {
                    int row = cc * 16 + l16;
                    int slot = ((kk * 4 + g) ^ (row & 7)) << 3;
                    bf16x8 kh = ld8(&sKh[row * 256 + slot]);
                    bf16x8 kl = ld8(&sKl[row * 256 + slot]);
                    c[cc] = MFMA16(qfh[kk], kh, c[cc]);
                    c[cc] = MFMA16(qfl[kk], kh, c[cc]);
                    c[cc] = MFMA16(qfh[kk], kl, c[cc]);
                }
            }
            __builtin_amdgcn_s_setprio(0);

            const bool full = (s0 + 31 <= q0) && (s0 >= q0 + 15 - (WIN - 1));
            #pragma unroll
            for (int r = 0; r < 4; ++r) {
                int qp = q0 + g * 4 + r;
                int row = g * 4 + r;
                #pragma unroll
                for (int cc = 0; cc < 2; ++cc) {
                    float ev = __expf(c[cc][r] * 0.04f);                       // e^{l/25}
                    float v = 50.f - 100.f * __builtin_amdgcn_rcpf(ev + 1.f);  // 50*tanh(l/50)
                    if (!full) {
                        int sp = s0 + cc * 16 + l16;
                        bool valid = (sp <= qp) && (sp > qp - WIN);
                        v = valid ? v : -1e30f;
                    }
                    float p = __expf(v - 20.f);       // fixed shift; masked -> exactly 0
                    u16 pb = f2bf(p);
                    pls[wave][row][cc * 16 + l16] = pb;
                    ssum[r] += bf2f(pb);
                }
            }
            bf16x8 pa = ld8(&pls[wave][l16][g * 8]);
            __builtin_amdgcn_s_setprio(1);
            #pragma unroll
            for (int jb = 0; jb < 16; ++jb)
                o[jb] = MFMA16(pa, ld8(&sV[(jb * 16 + l16) * 32 + g * 8]), o[jb]);
            __builtin_amdgcn_s_setprio(0);
        }
    }

    #pragma unroll
    for (int off = 1; off < 16; off <<= 1)
        #pragma unroll
        for (int r = 0; r < 4; ++r) ssum[r] += __shfl_xor(ssum[r], off);
    #pragma unroll
    for (int r = 0; r < 4; ++r) {
        float inv = 1.0f / ssum[r];
        int trow = q0 + g * 4 + r;
        size_t base = ((size_t)(b * SEQ + trow) * NH + hq) * 256 + l16;
        #pragma unroll
        for (int jb = 0; jb < 16; ++jb)
            Out[base + jb * 16] = f2bf(o[jb][r] * inv);
    }
}

extern "C" void kernel_launch(void* const* d_in, const int* in_sizes, int n_in,
                              void* d_out, int out_size, void* d_ws, size_t ws_size,
                              hipStream_t stream) {
    (void)in_sizes; (void)n_in; (void)out_size; (void)ws_size;
    const float* x  = (const float*)d_in[0];
    const int* pos  = (const int*)d_in[1];
    const float* wq = (const float*)d_in[3];
    const float* wk = (const float*)d_in[4];
    const float* wv = (const float*)d_in[5];
    const float* wo = (const float*)d_in[6];
    const float* qs = (const float*)d_in[7];
    const float* ks = (const float*)d_in[8];

    const size_t MX = (size_t)4096 * 2048;   // 8,388,608
    const size_t MW = (size_t)2048 * 2048;   // 4,194,304

    u16* xh  = (u16*)d_ws;
    u16* xl  = xh + MX;
    u16* wth = xl + MX;
    u16* wtl = wth + MX;
    u16* woth = wtl + MX;
    u16* wotl = woth + MW;
    float* qkv = (float*)(wotl + MW);

    u16* qbh = xh;               // 8M
    u16* qbl = qbh + MX;         // 8M
    u16* kbh = qbl + MX;         // 4M
    u16* kbl = kbh + MX / 2;     // 4M
    u16* vt  = kbl + MX / 2;     // 4M
    u16* ao  = (u16*)qkv;        // aliases region C (plain bf16)

    k_prep<<<11264, 256, 0, stream>>>(x, xh, xl,
                                      wq, wth, wtl,
                                      wk, wth + MW, wtl + MW,
                                      wv, wth + MW + MW / 2,
                                      wo, woth);
    k_gemm1<<<dim3(32, 32), 256, 0, stream>>>(xh, xl, wth, wtl, qkv,
                                              4096, 4096, 2048, 3072);
    k_nrvt<<<13312, 256, 0, stream>>>(qkv, pos, qs, ks, qbh, qbl, kbh, kbl, vt);
    k_attn<<<512, 256, 0, stream>>>(qbh, qbl, kbh, kbl, vt, ao);
    k_gemm<<<dim3(32, 16), 256, 0, stream>>>(ao, woth, ao, woth, ao, wotl, (float*)d_out,
                                             4096, 2048, 2048, 1, 2048);
}